// Round 10
// baseline (139.088 us; speedup 1.0000x reference)
//
#include <hip/hip_runtime.h>
#include <stdint.h>
#include <stddef.h>

// GRIT attention, MI355X bf16-MFMA implementation, round 21.
// = R18 (137.7 us best: 4 kernels, xb staging, fused normalize) with k_flash
//   restructured to restore R13's 16 waves/CU without re-adding k_comb:
//   - 512 blocks x 8 waves (zg x ih x jq = 2x2x2): the KV-split moves INSIDE
//     the block. Each 4-wave group (zg) streams its own KV half (32 steps of
//     64) into its own K/V double-buffers; combine is a 2-stage in-LDS tree
//     (jq-combine, then zg-combine) + normalize + bf16 store. No global
//     partials, no atomics.
//   - LDS 73728 B (Q 8K | K 4x8K | V 4x8K) -> 2 blocks/CU = 16 waves/CU
//     (R13-parity; R18's 8 waves/CU cost +10% on the latency-chain-bound
//     flash: 0.40 vs 0.362 us per unit work).
//   - s_setprio(1) around both MFMA clusters (T5 isolated, m191 +4-7% attn;
//     R17's null was confounded by its triple-buffer regression).
// k_gemm_qkv reverted to R18's 64x128 version (R20's 128^2 was +0.9 us).

typedef unsigned short u16;
typedef __attribute__((ext_vector_type(8))) short short8;
typedef __attribute__((ext_vector_type(8))) unsigned short us8;
typedef __attribute__((ext_vector_type(4))) unsigned short us4;
typedef __attribute__((ext_vector_type(4))) float floatx4;

__device__ __forceinline__ u16 f2b(float f) {
  union { float f; uint32_t u; } v; v.f = f;
  uint32_t u = v.u;
  return (u16)((u + 0x7fffu + ((u >> 16) & 1u)) >> 16);  // RNE
}

// pack two f32 -> two bf16 (round-half-up): add, add, v_perm
__device__ __forceinline__ uint32_t pkbf16(float a, float b) {
  union { float f; uint32_t u; } x, y; x.f = a; y.f = b;
  return __builtin_amdgcn_perm(y.u + 0x8000u, x.u + 0x8000u, 0x07060302u);
}

#if __has_builtin(__builtin_amdgcn_exp2f)
__device__ __forceinline__ float fexp2(float x) { return __builtin_amdgcn_exp2f(x); }
#else
__device__ __forceinline__ float fexp2(float x) { return exp2f(x); }
#endif

__device__ __forceinline__ void gld16(const u16* g, u16* l) {
  __builtin_amdgcn_global_load_lds(
      (const __attribute__((address_space(1))) uint32_t*)(const void*)g,
      (__attribute__((address_space(3))) uint32_t*)(void*)l, 16, 0, 0);
}

// ---------------- fused prep ----------------

__device__ __forceinline__ void tr_tile(const float* __restrict__ in,
                                        u16* __restrict__ out, int R, int C,
                                        int bx, int by, u16 (*tile)[33]) {
  int tx = threadIdx.x & 31, ty = threadIdx.x >> 5;
  int c0 = bx * 32, r0 = by * 32;
#pragma unroll
  for (int i = 0; i < 32; i += 8)
    tile[ty + i][tx] = f2b(in[(size_t)(r0 + ty + i) * C + c0 + tx]);
  __syncthreads();
#pragma unroll
  for (int i = 0; i < 32; i += 8)
    out[(size_t)(c0 + ty + i) * R + r0 + tx] = tile[tx][ty + i];
}

__global__ __launch_bounds__(256) void k_prep(
    const float* __restrict__ x, u16* __restrict__ xb,
    const float* __restrict__ w_qkv, u16* __restrict__ wqkvT,
    const float* __restrict__ w_out, u16* __restrict__ woutT,
    const float* __restrict__ pe, const float* __restrict__ w_pe,
    const float* __restrict__ b_pe, float* __restrict__ wexp,
    u16* __restrict__ wpb) {
  __shared__ u16 tile[32][33];
  int b = blockIdx.x;
  if (b < 2048) {
    int i = b * 256 + threadIdx.x;
    float4 v = ((const float4*)x)[i];
    uint2 o = make_uint2(pkbf16(v.x, v.y), pkbf16(v.z, v.w));
    ((uint2*)xb)[i] = o;
  } else if (b < 2816) {
    int idx = b - 2048;
    tr_tile(w_qkv, wqkvT, 512, 1536, idx % 48, idx / 48, tile);
  } else if (b < 3072) {
    int idx = b - 2816;
    tr_tile(w_out, woutT, 512, 512, idx % 16, idx / 16, tile);
  } else {
    int idx = (b - 3072) * 256 + threadIdx.x;
    int h = idx >> 12, n = idx & 4095;
    float acc = b_pe[h];
#pragma unroll
    for (int d = 0; d < 16; ++d) acc = fmaf(pe[n * 16 + d], w_pe[d * 8 + h], acc);
    float w = exp2f(acc * 1.4426950408889634f - 16.0f);
    u16 wb = f2b(w);
    union { uint32_t u; float f; } cv; cv.u = ((uint32_t)wb) << 16;
    wexp[h * 4096 + n] = cv.f;  // the SAME bf16-rounded value V' will use
    int pn = (n & ~31) | (((n >> 2) & 3) << 3) | (((n >> 4) & 1) << 2) | (n & 3);
    wpb[h * 4096 + pn] = wb;    // pi-permuted for flash's l B-frag
  }
}

// ---------------- QKV GEMM: 64x128 tile, BK=64, 512 thr, async dbuf ---------
// Q cols (<512) pre-scaled by 0.125*log2e; V cols pre-multiplied by w~ and
// written transposed+pi-permuted to vtp[d][4096] via an LDS transpose buffer.

__global__ __launch_bounds__(512, 6) void k_gemm_qkv(const u16* __restrict__ A,
                                                     const u16* __restrict__ Bt,
                                                     const float* __restrict__ bias,
                                                     const float* __restrict__ wexp,
                                                     u16* __restrict__ qk,
                                                     u16* __restrict__ vtp) {
  __shared__ __align__(16) u16 smem[24576];  // As 2x4096 @0, Bs 2x8192 @8192
  const int tid = threadIdx.x;
  const int lane = tid & 63, wave = tid >> 6;
  const int colx = lane & 15, quad = lane >> 4;
  const int m0 = blockIdx.y * 64, n0 = blockIdx.x * 128;
  const int wm = wave >> 2, wn = wave & 3;
  const int sc = (lane & 7) ^ ((lane >> 3) & 7);
  const floatx4 fz = {0.f, 0.f, 0.f, 0.f};
  floatx4 acc[2][2];
#pragma unroll
  for (int i = 0; i < 2; ++i)
#pragma unroll
    for (int j = 0; j < 2; ++j) acc[i][j] = fz;

#define PREF_QKV(k0, b)                                                       \
  {                                                                           \
    int rowa = wave * 8 + (lane >> 3);                                        \
    gld16(&A[(size_t)(m0 + rowa) * 512 + (k0) + sc * 8],                      \
          &smem[(b) * 4096 + wave * 512 + lane * 8]);                         \
    _Pragma("unroll") for (int c = 0; c < 2; ++c) {                           \
      int rowb = wave * 16 + c * 8 + (lane >> 3);                             \
      gld16(&Bt[(size_t)(n0 + rowb) * 512 + (k0) + sc * 8],                   \
            &smem[8192 + (b) * 8192 + wave * 1024 + c * 512 + lane * 8]);     \
    }                                                                         \
  }

  PREF_QKV(0, 0);
  __syncthreads();
  for (int it = 0; it < 8; ++it) {
    int cur = it & 1;
    if (it < 7) PREF_QKV((it + 1) * 64, cur ^ 1);
    const u16* As = &smem[cur * 4096];
    const u16* Bs = &smem[8192 + cur * 8192];
#pragma unroll
    for (int kk = 0; kk < 2; ++kk) {
      short8 af[2], bf[2];
#pragma unroll
      for (int i = 0; i < 2; ++i) {
        int row = wm * 32 + i * 16 + colx;
        af[i] = *(const short8*)&As[row * 64 + (((kk * 4 + quad) ^ (colx & 7))) * 8];
      }
#pragma unroll
      for (int j = 0; j < 2; ++j) {
        int row = wn * 32 + j * 16 + colx;
        bf[j] = *(const short8*)&Bs[row * 64 + (((kk * 4 + quad) ^ (colx & 7))) * 8];
      }
#pragma unroll
      for (int i = 0; i < 2; ++i)
#pragma unroll
        for (int j = 0; j < 2; ++j)
          acc[i][j] = __builtin_amdgcn_mfma_f32_16x16x32_bf16(af[i], bf[j], acc[i][j], 0, 0, 0);
    }
    __syncthreads();
  }

  const bool isV = (blockIdx.x >= 8);
  if (!isV) {
#pragma unroll
    for (int j = 0; j < 2; ++j) {
      int c = n0 + wn * 32 + j * 16 + colx;
      float bq = bias[c];
      float qs = (c < 512) ? 0.18033688011112042f : 1.0f;  // 0.125*log2(e)
#pragma unroll
      for (int i = 0; i < 2; ++i)
#pragma unroll
        for (int r = 0; r < 4; ++r) {
          int row = m0 + wm * 32 + i * 16 + quad * 4 + r;
          qk[(size_t)row * 1024 + c] = f2b((acc[i][j][r] + bq) * qs);
        }
    }
  } else {
    // V: w~-fold + transpose + pi through LDS, then coalesced us8 stores.
    const int dv = n0 - 1024;
    u16* Vl = smem;  // [128 d][72] u16 (stride 144B == 16 mod 128: staggered)
    const int hh = (dv + wn * 32) >> 6;  // GLOBAL head; same for j=0,1
#pragma unroll
    for (int j = 0; j < 2; ++j) {
      float bq = bias[n0 + wn * 32 + j * 16 + colx];
#pragma unroll
      for (int i = 0; i < 2; ++i) {
        floatx4 wv = *(const floatx4*)&wexp[hh * 4096 + m0 + wm * 32 + i * 16 + quad * 4];
        us4 o;
#pragma unroll
        for (int r = 0; r < 4; ++r) o[r] = f2b((acc[i][j][r] + bq) * wv[r]);
        int dl = wn * 32 + j * 16 + colx;          // local d 0..127
        int nc = wm * 32 + quad * 8 + i * 4;       // pi-permuted local n
        *(us4*)&Vl[dl * 72 + nc] = o;
      }
    }
    __syncthreads();
#pragma unroll
    for (int t = 0; t < 2; ++t) {
      int idx = t * 512 + tid;
      int dl = idx >> 3, ch = idx & 7;
      *(us8*)&vtp[(size_t)(dv + dl) * 4096 + m0 + ch * 8] =
          *(const us8*)&Vl[dl * 72 + ch * 8];
    }
  }
#undef PREF_QKV
}

// ---------------- flash (fixed-max, linear, in-block KV-split, w-folded) ----
// grid (64 q-tiles, 8 heads), 512 thr = 8 waves = zg(2) x ih(2) x jq(2).
// Each zg group streams its own KV half (32 steps of 64) into its own K/V
// double buffers; 32 q rows per wave. LDS 73728 B: Q 8K | K 4x8K | V 4x8K
// -> 2 blocks/CU = 16 waves/CU. Epilogue: jq-combine then zg-combine in LDS,
// normalize (O * 1/l), store bf16.

__global__ __launch_bounds__(512, 4) void k_flash(const u16* __restrict__ qk,
                                                  const u16* __restrict__ vt,
                                                  const u16* __restrict__ wpb,
                                                  u16* __restrict__ ao) {
  __shared__ __align__(16) u16 smem[36864];  // 73728 B
  float* bufs = (float*)smem;                // epilogue overlay 4 x 32x65 f32

  const int tid = threadIdx.x;
  const int lane = tid & 63, wave = tid >> 6;
  const int colx = lane & 15, quad = lane >> 4;
  const int zg = wave >> 2;            // kv-half group
  const int ih = (wave >> 1) & 1, jq = wave & 1;
  const int gw = wave & 3;             // wave index within group
  const int q0 = blockIdx.x * 64;
  const int h = blockIdx.y;
  const int kvb = zg * 2048;
  const floatx4 fz = {0.f, 0.f, 0.f, 0.f};

  const int sc = (lane & 7) ^ ((lane >> 3) & 7);
  const int srow = gw * 16 + (lane >> 3);

  // stage Q (swizzled ds_write): 64 rows x 64 cols, one pass of 512 thr
  {
    int row = tid >> 3, ch = tid & 7;
    *(us8*)&smem[row * 64 + (ch ^ (row & 7)) * 8] =
        *(const us8*)&qk[(size_t)(q0 + row) * 1024 + h * 64 + ch * 8];
  }
  // prefetch tile 0 (per group): 4 waves stage 64 K rows + 64 V^T rows
  const u16* qptr = qk + (size_t)(kvb + srow) * 1024 + 512 + h * 64 + sc * 8;
  const u16* vptr = vt + (size_t)(h * 64 + srow) * 4096 + kvb + sc * 8;
  const u16* wptr = wpb + h * 4096 + kvb + jq * 32 + quad * 8;
  gld16(qptr, &smem[4096 + (zg * 2) * 4096 + gw * 1024 + lane * 8]);
  gld16(qptr + 8192, &smem[4096 + (zg * 2) * 4096 + gw * 1024 + 512 + lane * 8]);
  gld16(vptr, &smem[20480 + (zg * 2) * 4096 + gw * 1024 + lane * 8]);
  gld16(vptr + 32768, &smem[20480 + (zg * 2) * 4096 + gw * 1024 + 512 + lane * 8]);
  qptr += 65536;  // 64 kv rows * 1024
  vptr += 64;     // 64 kv cols
  __syncthreads();

  short8 qf[2][2];
#pragma unroll
  for (int iq = 0; iq < 2; ++iq)
#pragma unroll
    for (int kk = 0; kk < 2; ++kk) {
      int row = ih * 32 + iq * 16 + colx;
      qf[iq][kk] = *(const short8*)&smem[row * 64 + (((kk * 4 + quad) ^ (colx & 7))) * 8];
    }

  floatx4 oacc[2][4], lacc[2];
  lacc[0] = fz; lacc[1] = fz;
#pragma unroll
  for (int iq = 0; iq < 2; ++iq)
#pragma unroll
    for (int cb = 0; cb < 4; ++cb) oacc[iq][cb] = fz;

#define FBODY(CUR, PREF)                                                      \
  {                                                                           \
    short8 wf = *(const short8*)wptr;                                         \
    wptr += 64;                                                               \
    if (PREF) {                                                               \
      gld16(qptr, &smem[4096 + (zg * 2 + 1 - (CUR)) * 4096 + gw * 1024 + lane * 8]); \
      gld16(qptr + 8192,                                                      \
            &smem[4096 + (zg * 2 + 1 - (CUR)) * 4096 + gw * 1024 + 512 + lane * 8]); \
      gld16(vptr, &smem[20480 + (zg * 2 + 1 - (CUR)) * 4096 + gw * 1024 + lane * 8]); \
      gld16(vptr + 32768,                                                     \
            &smem[20480 + (zg * 2 + 1 - (CUR)) * 4096 + gw * 1024 + 512 + lane * 8]); \
      qptr += 65536;                                                          \
      vptr += 64;                                                             \
    }                                                                         \
    const u16* Ks = &smem[4096 + (zg * 2 + (CUR)) * 4096];                    \
    const u16* Vts = &smem[20480 + (zg * 2 + (CUR)) * 4096];                  \
    floatx4 sacc[2][2] = {{fz, fz}, {fz, fz}};                                \
    __builtin_amdgcn_s_setprio(1);                                            \
    _Pragma("unroll") for (int j2 = 0; j2 < 2; ++j2) {                        \
      _Pragma("unroll") for (int kk = 0; kk < 2; ++kk) {                      \
        int row = jq * 32 + j2 * 16 + colx;                                   \
        short8 kf = *(const short8*)&Ks[row * 64 +                            \
                                        (((kk * 4 + quad) ^ (colx & 7))) * 8];\
        sacc[0][j2] = __builtin_amdgcn_mfma_f32_16x16x32_bf16(                \
            kf, qf[0][kk], sacc[0][j2], 0, 0, 0);                             \
        sacc[1][j2] = __builtin_amdgcn_mfma_f32_16x16x32_bf16(                \
            kf, qf[1][kk], sacc[1][j2], 0, 0, 0);                             \
      }                                                                       \
    }                                                                         \
    __builtin_amdgcn_s_setprio(0);                                            \
    union { uint32_t w[4]; short8 s; } pk[2];                                 \
    _Pragma("unroll") for (int iq = 0; iq < 2; ++iq) {                        \
      _Pragma("unroll") for (int j2 = 0; j2 < 2; ++j2) {                      \
        float p0 = fexp2(sacc[iq][j2][0]);                                    \
        float p1 = fexp2(sacc[iq][j2][1]);                                    \
        float p2 = fexp2(sacc[iq][j2][2]);                                    \
        float p3 = fexp2(sacc[iq][j2][3]);                                    \
        pk[iq].w[j2 * 2 + 0] = pkbf16(p0, p1);                                \
        pk[iq].w[j2 * 2 + 1] = pkbf16(p2, p3);                                \
      }                                                                       \
    }                                                                         \
    __builtin_amdgcn_s_setprio(1);                                            \
    _Pragma("unroll") for (int cb = 0; cb < 4; ++cb) {                        \
      int row = cb * 16 + colx;                                               \
      short8 vf = *(const short8*)&Vts[row * 64 +                             \
                                       (((jq * 4 + quad) ^ (colx & 7))) * 8]; \
      oacc[0][cb] = __builtin_amdgcn_mfma_f32_16x16x32_bf16(                  \
          pk[0].s, vf, oacc[0][cb], 0, 0, 0);                                 \
      oacc[1][cb] = __builtin_amdgcn_mfma_f32_16x16x32_bf16(                  \
          pk[1].s, vf, oacc[1][cb], 0, 0, 0);                                 \
    }                                                                         \
    lacc[0] = __builtin_amdgcn_mfma_f32_16x16x32_bf16(pk[0].s, wf, lacc[0], 0, 0, 0); \
    lacc[1] = __builtin_amdgcn_mfma_f32_16x16x32_bf16(pk[1].s, wf, lacc[1], 0, 0, 0); \
    __builtin_amdgcn_s_setprio(0);                                            \
    __syncthreads();                                                          \
  }

  for (int t = 0; t < 15; ++t) {
    FBODY(0, 1)
    FBODY(1, 1)
  }
  FBODY(0, 1)
  FBODY(1, 0)
#undef FBODY

  // ---- combine tree ----
  // stage 1 (within zg): jq==1 writes to slot (zg*2+ih); jq==0 adds.
  float* b1 = bufs + (zg * 2 + ih) * 2080;  // 32 rows x 65 f32
  if (jq == 1) {
#pragma unroll
    for (int iq = 0; iq < 2; ++iq)
#pragma unroll
      for (int cb = 0; cb < 4; ++cb)
#pragma unroll
        for (int r = 0; r < 4; ++r)
          b1[(iq * 16 + quad * 4 + r) * 65 + cb * 16 + colx] = oacc[iq][cb][r];
    if (colx == 0)
#pragma unroll
      for (int iq = 0; iq < 2; ++iq)
#pragma unroll
        for (int r = 0; r < 4; ++r) b1[(iq * 16 + quad * 4 + r) * 65 + 64] = lacc[iq][r];
  }
  __syncthreads();
  if (jq == 0) {
#pragma unroll
    for (int iq = 0; iq < 2; ++iq) {
#pragma unroll
      for (int cb = 0; cb < 4; ++cb)
#pragma unroll
        for (int r = 0; r < 4; ++r)
          oacc[iq][cb][r] += b1[(iq * 16 + quad * 4 + r) * 65 + cb * 16 + colx];
#pragma unroll
      for (int r = 0; r < 4; ++r) lacc[iq][r] += b1[(iq * 16 + quad * 4 + r) * 65 + 64];
    }
  }
  __syncthreads();
  // stage 2 (across zg): zg==1,jq==0 writes to slot ih; zg==0,jq==0 combines.
  float* b2 = bufs + ih * 2080;
  if (zg == 1 && jq == 0) {
#pragma unroll
    for (int iq = 0; iq < 2; ++iq)
#pragma unroll
      for (int cb = 0; cb < 4; ++cb)
#pragma unroll
        for (int r = 0; r < 4; ++r)
          b2[(iq * 16 + quad * 4 + r) * 65 + cb * 16 + colx] = oacc[iq][cb][r];
    if (colx == 0)
#pragma unroll
      for (int iq = 0; iq < 2; ++iq)
#pragma unroll
        for (int r = 0; r < 4; ++r) b2[(iq * 16 + quad * 4 + r) * 65 + 64] = lacc[iq][r];
  }
  __syncthreads();
  if (zg == 0 && jq == 0) {
#pragma unroll
    for (int iq = 0; iq < 2; ++iq) {
#pragma unroll
      for (int cb = 0; cb < 4; ++cb)
#pragma unroll
        for (int r = 0; r < 4; ++r)
          oacc[iq][cb][r] += b2[(iq * 16 + quad * 4 + r) * 65 + cb * 16 + colx];
#pragma unroll
      for (int r = 0; r < 4; ++r) lacc[iq][r] += b2[(iq * 16 + quad * 4 + r) * 65 + 64];
    }
#pragma unroll
    for (int iq = 0; iq < 2; ++iq) {
      float inv[4];
#pragma unroll
      for (int r = 0; r < 4; ++r) inv[r] = 1.0f / lacc[iq][r];
#pragma unroll
      for (int cb = 0; cb < 4; ++cb)
#pragma unroll
        for (int r = 0; r < 4; ++r) {
          int row = q0 + ih * 32 + iq * 16 + quad * 4 + r;
          ao[(size_t)row * 512 + h * 64 + cb * 16 + colx] =
              f2b(oacc[iq][cb][r] * inv[r]);
        }
    }
  }
}

// ---------------- out GEMM: 64x64 tile, BK=64, 512 thr, async dbuf ----------

__global__ __launch_bounds__(512, 4) void k_gemm_out(const u16* __restrict__ A,
                                                     const u16* __restrict__ Bt,
                                                     const float* __restrict__ bias,
                                                     float* __restrict__ Cout) {
  __shared__ __align__(16) u16 smem[16384];  // As 2x4096 @0, Bs 2x4096 @8192
  const int tid = threadIdx.x;
  const int lane = tid & 63, wave = tid >> 6;
  const int colx = lane & 15, quad = lane >> 4;
  const int m0 = blockIdx.y * 64, n0 = blockIdx.x * 64;
  const int wm = wave >> 2, wn = wave & 3;
  const int sc = (lane & 7) ^ ((lane >> 3) & 7);
  const floatx4 fz = {0.f, 0.f, 0.f, 0.f};
  floatx4 acc[2];
  acc[0] = fz; acc[1] = fz;

#define PREF_OUT(k0, b)                                                       \
  {                                                                           \
    int rowa = wave * 8 + (lane >> 3);                                        \
    gld16(&A[(size_t)(m0 + rowa) * 512 + (k0) + sc * 8],                      \
          &smem[(b) * 4096 + wave * 512 + lane * 8]);                         \
    gld16(&Bt[(size_t)(n0 + rowa) * 512 + (k0) + sc * 8],                     \
          &smem[8192 + (b) * 4096 + wave * 512 + lane * 8]);                  \
  }

  PREF_OUT(0, 0);
  __syncthreads();
  for (int it = 0; it < 8; ++it) {
    int cur = it & 1;
    if (it < 7) PREF_OUT((it + 1) * 64, cur ^ 1);
    const u16* As = &smem[cur * 4096];
    const u16* Bs = &smem[8192 + cur * 4096];
#pragma unroll
    for (int kk = 0; kk < 2; ++kk) {
      short8 af[2], bf;
#pragma unroll
      for (int i = 0; i < 2; ++i) {
        int row = wm * 32 + i * 16 + colx;
        af[i] = *(const short8*)&As[row * 64 + (((kk * 4 + quad) ^ (colx & 7))) * 8];
      }
      {
        int row = wn * 16 + colx;
        bf = *(const short8*)&Bs[row * 64 + (((kk * 4 + quad) ^ (colx & 7))) * 8];
      }
#pragma unroll
      for (int i = 0; i < 2; ++i)
        acc[i] = __builtin_amdgcn_mfma_f32_16x16x32_bf16(af[i], bf, acc[i], 0, 0, 0);
    }
    __syncthreads();
  }
  int c = n0 + wn * 16 + colx;
  float bq = bias[c];
#pragma unroll
  for (int i = 0; i < 2; ++i)
#pragma unroll
    for (int r = 0; r < 4; ++r) {
      int row = m0 + wm * 32 + i * 16 + quad * 4 + r;
      Cout[(size_t)row * 512 + c] = acc[i][r] + bq;
    }
#undef PREF_OUT
}

// ---------------- launch ----------------

extern "C" void kernel_launch(void* const* d_in, const int* in_sizes, int n_in,
                              void* d_out, int out_size, void* d_ws, size_t ws_size,
                              hipStream_t stream) {
  const float* x     = (const float*)d_in[0];
  const float* pe    = (const float*)d_in[1];
  const float* w_qkv = (const float*)d_in[2];
  const float* b_qkv = (const float*)d_in[3];
  const float* w_pe  = (const float*)d_in[4];
  const float* b_pe  = (const float*)d_in[5];
  const float* w_out = (const float*)d_in[6];
  const float* b_out = (const float*)d_in[7];
  float* out = (float*)d_out;

  // workspace layout
  u16* xb    = (u16*)d_ws;              // 4096*512
  u16* wqkvT = xb    + 2097152;         // 1536*512
  u16* woutT = wqkvT + 786432;          // 512*512
  u16* qk    = woutT + 262144;          // 4096*1024 (Q'|K)
  u16* vt    = qk    + 4194304;         // 512*4096 (pi-permuted w~-folded V'^T)
  u16* wpb   = vt    + 2097152;         // 8*4096 bf16 (pi-permuted w~)
  u16* ao    = wpb   + 32768;           // 4096*512 bf16
  float* wexp  = (float*)(ao + 2097152); // 8*4096 f32 (same w~, expanded)

  k_prep<<<3200, 256, 0, stream>>>(x, xb, w_qkv, wqkvT, w_out, woutT,
                                   pe, w_pe, b_pe, wexp, wpb);
  k_gemm_qkv<<<dim3(12, 64), 512, 0, stream>>>(xb, wqkvT, b_qkv, wexp, qk, vt);
  k_flash<<<dim3(64, 8), 512, 0, stream>>>(qk, vt, wpb, ao);
  k_gemm_out<<<dim3(8, 64), 512, 0, stream>>>(ao, woutT, b_out, out);
}

// Round 11
// 136.079 us; speedup vs baseline: 1.0221x; 1.0221x over previous
//
#include <hip/hip_runtime.h>
#include <stdint.h>
#include <stddef.h>

// GRIT attention, MI355X bf16-MFMA implementation, round 22.
// = R21 (k_flash: in-block KV-split, 16 waves/CU, setprio — 47.4 us measured)
//   + k_gemm_qkv Q/K epilogue rebuilt like the V path: stage the 64x128
//   result tile in LDS [64][136] u16 (272 B stride == 16 mod 128 stagger),
//   then coalesced us8 stores (16 B/lane) instead of 2-byte scalar scattered
//   stores (4 rows x 32 B segments per wave op, ~4x transactions on 8 MB).
// Ledger: flash at structural floor (MFMA-issue ~18.7 us + 16 exps/lane/step
//   VALU ~15-20 us, partial overlap); totals noise +-2 us; this round's
//   target is the last identifiable >=2 us inefficiency outside flash.

typedef unsigned short u16;
typedef __attribute__((ext_vector_type(8))) short short8;
typedef __attribute__((ext_vector_type(8))) unsigned short us8;
typedef __attribute__((ext_vector_type(4))) unsigned short us4;
typedef __attribute__((ext_vector_type(4))) float floatx4;

__device__ __forceinline__ u16 f2b(float f) {
  union { float f; uint32_t u; } v; v.f = f;
  uint32_t u = v.u;
  return (u16)((u + 0x7fffu + ((u >> 16) & 1u)) >> 16);  // RNE
}

// pack two f32 -> two bf16 (round-half-up): add, add, v_perm
__device__ __forceinline__ uint32_t pkbf16(float a, float b) {
  union { float f; uint32_t u; } x, y; x.f = a; y.f = b;
  return __builtin_amdgcn_perm(y.u + 0x8000u, x.u + 0x8000u, 0x07060302u);
}

#if __has_builtin(__builtin_amdgcn_exp2f)
__device__ __forceinline__ float fexp2(float x) { return __builtin_amdgcn_exp2f(x); }
#else
__device__ __forceinline__ float fexp2(float x) { return exp2f(x); }
#endif

__device__ __forceinline__ void gld16(const u16* g, u16* l) {
  __builtin_amdgcn_global_load_lds(
      (const __attribute__((address_space(1))) uint32_t*)(const void*)g,
      (__attribute__((address_space(3))) uint32_t*)(void*)l, 16, 0, 0);
}

// ---------------- fused prep ----------------

__device__ __forceinline__ void tr_tile(const float* __restrict__ in,
                                        u16* __restrict__ out, int R, int C,
                                        int bx, int by, u16 (*tile)[33]) {
  int tx = threadIdx.x & 31, ty = threadIdx.x >> 5;
  int c0 = bx * 32, r0 = by * 32;
#pragma unroll
  for (int i = 0; i < 32; i += 8)
    tile[ty + i][tx] = f2b(in[(size_t)(r0 + ty + i) * C + c0 + tx]);
  __syncthreads();
#pragma unroll
  for (int i = 0; i < 32; i += 8)
    out[(size_t)(c0 + ty + i) * R + r0 + tx] = tile[tx][ty + i];
}

__global__ __launch_bounds__(256) void k_prep(
    const float* __restrict__ x, u16* __restrict__ xb,
    const float* __restrict__ w_qkv, u16* __restrict__ wqkvT,
    const float* __restrict__ w_out, u16* __restrict__ woutT,
    const float* __restrict__ pe, const float* __restrict__ w_pe,
    const float* __restrict__ b_pe, float* __restrict__ wexp,
    u16* __restrict__ wpb) {
  __shared__ u16 tile[32][33];
  int b = blockIdx.x;
  if (b < 2048) {
    int i = b * 256 + threadIdx.x;
    float4 v = ((const float4*)x)[i];
    uint2 o = make_uint2(pkbf16(v.x, v.y), pkbf16(v.z, v.w));
    ((uint2*)xb)[i] = o;
  } else if (b < 2816) {
    int idx = b - 2048;
    tr_tile(w_qkv, wqkvT, 512, 1536, idx % 48, idx / 48, tile);
  } else if (b < 3072) {
    int idx = b - 2816;
    tr_tile(w_out, woutT, 512, 512, idx % 16, idx / 16, tile);
  } else {
    int idx = (b - 3072) * 256 + threadIdx.x;
    int h = idx >> 12, n = idx & 4095;
    float acc = b_pe[h];
#pragma unroll
    for (int d = 0; d < 16; ++d) acc = fmaf(pe[n * 16 + d], w_pe[d * 8 + h], acc);
    float w = exp2f(acc * 1.4426950408889634f - 16.0f);
    u16 wb = f2b(w);
    union { uint32_t u; float f; } cv; cv.u = ((uint32_t)wb) << 16;
    wexp[h * 4096 + n] = cv.f;  // the SAME bf16-rounded value V' will use
    int pn = (n & ~31) | (((n >> 2) & 3) << 3) | (((n >> 4) & 1) << 2) | (n & 3);
    wpb[h * 4096 + pn] = wb;    // pi-permuted for flash's l B-frag
  }
}

// ---------------- QKV GEMM: 64x128 tile, BK=64, 512 thr, async dbuf ---------
// Q cols (<512) pre-scaled by 0.125*log2e; V cols pre-multiplied by w~ and
// written transposed+pi-permuted to vtp[d][4096] via an LDS transpose buffer.
// Q/K epilogue also goes through LDS for coalesced us8 stores (R22).

__global__ __launch_bounds__(512, 6) void k_gemm_qkv(const u16* __restrict__ A,
                                                     const u16* __restrict__ Bt,
                                                     const float* __restrict__ bias,
                                                     const float* __restrict__ wexp,
                                                     u16* __restrict__ qk,
                                                     u16* __restrict__ vtp) {
  __shared__ __align__(16) u16 smem[24576];  // As 2x4096 @0, Bs 2x8192 @8192
  const int tid = threadIdx.x;
  const int lane = tid & 63, wave = tid >> 6;
  const int colx = lane & 15, quad = lane >> 4;
  const int m0 = blockIdx.y * 64, n0 = blockIdx.x * 128;
  const int wm = wave >> 2, wn = wave & 3;
  const int sc = (lane & 7) ^ ((lane >> 3) & 7);
  const floatx4 fz = {0.f, 0.f, 0.f, 0.f};
  floatx4 acc[2][2];
#pragma unroll
  for (int i = 0; i < 2; ++i)
#pragma unroll
    for (int j = 0; j < 2; ++j) acc[i][j] = fz;

#define PREF_QKV(k0, b)                                                       \
  {                                                                           \
    int rowa = wave * 8 + (lane >> 3);                                        \
    gld16(&A[(size_t)(m0 + rowa) * 512 + (k0) + sc * 8],                      \
          &smem[(b) * 4096 + wave * 512 + lane * 8]);                         \
    _Pragma("unroll") for (int c = 0; c < 2; ++c) {                           \
      int rowb = wave * 16 + c * 8 + (lane >> 3);                             \
      gld16(&Bt[(size_t)(n0 + rowb) * 512 + (k0) + sc * 8],                   \
            &smem[8192 + (b) * 8192 + wave * 1024 + c * 512 + lane * 8]);     \
    }                                                                         \
  }

  PREF_QKV(0, 0);
  __syncthreads();
  for (int it = 0; it < 8; ++it) {
    int cur = it & 1;
    if (it < 7) PREF_QKV((it + 1) * 64, cur ^ 1);
    const u16* As = &smem[cur * 4096];
    const u16* Bs = &smem[8192 + cur * 8192];
#pragma unroll
    for (int kk = 0; kk < 2; ++kk) {
      short8 af[2], bf[2];
#pragma unroll
      for (int i = 0; i < 2; ++i) {
        int row = wm * 32 + i * 16 + colx;
        af[i] = *(const short8*)&As[row * 64 + (((kk * 4 + quad) ^ (colx & 7))) * 8];
      }
#pragma unroll
      for (int j = 0; j < 2; ++j) {
        int row = wn * 32 + j * 16 + colx;
        bf[j] = *(const short8*)&Bs[row * 64 + (((kk * 4 + quad) ^ (colx & 7))) * 8];
      }
#pragma unroll
      for (int i = 0; i < 2; ++i)
#pragma unroll
        for (int j = 0; j < 2; ++j)
          acc[i][j] = __builtin_amdgcn_mfma_f32_16x16x32_bf16(af[i], bf[j], acc[i][j], 0, 0, 0);
    }
    __syncthreads();
  }

  const bool isV = (blockIdx.x >= 8);
  if (!isV) {
    // Q/K: bias+scale, stage in LDS [64][136], then coalesced us8 stores.
    u16* Ql = smem;
#pragma unroll
    for (int j = 0; j < 2; ++j) {
      int c = n0 + wn * 32 + j * 16 + colx;
      float bq = bias[c];
      float qs = (c < 512) ? 0.18033688011112042f : 1.0f;  // 0.125*log2(e)
#pragma unroll
      for (int i = 0; i < 2; ++i)
#pragma unroll
        for (int r = 0; r < 4; ++r) {
          int rl = wm * 32 + i * 16 + quad * 4 + r;          // local row 0..63
          int cl = wn * 32 + j * 16 + colx;                  // local col 0..127
          Ql[rl * 136 + cl] = f2b((acc[i][j][r] + bq) * qs);
        }
    }
    __syncthreads();
#pragma unroll
    for (int t = 0; t < 2; ++t) {
      int idx = t * 512 + tid;        // 1024 chunks = 64 rows x 16 chunks
      int rl = idx >> 4, ch = idx & 15;
      *(us8*)&qk[(size_t)(m0 + rl) * 1024 + n0 + ch * 8] =
          *(const us8*)&Ql[rl * 136 + ch * 8];
    }
  } else {
    // V: w~-fold + transpose + pi through LDS, then coalesced us8 stores.
    const int dv = n0 - 1024;
    u16* Vl = smem;  // [128 d][72] u16 (stride 144B == 16 mod 128: staggered)
    const int hh = (dv + wn * 32) >> 6;  // GLOBAL head; same for j=0,1
#pragma unroll
    for (int j = 0; j < 2; ++j) {
      float bq = bias[n0 + wn * 32 + j * 16 + colx];
#pragma unroll
      for (int i = 0; i < 2; ++i) {
        floatx4 wv = *(const floatx4*)&wexp[hh * 4096 + m0 + wm * 32 + i * 16 + quad * 4];
        us4 o;
#pragma unroll
        for (int r = 0; r < 4; ++r) o[r] = f2b((acc[i][j][r] + bq) * wv[r]);
        int dl = wn * 32 + j * 16 + colx;          // local d 0..127
        int nc = wm * 32 + quad * 8 + i * 4;       // pi-permuted local n
        *(us4*)&Vl[dl * 72 + nc] = o;
      }
    }
    __syncthreads();
#pragma unroll
    for (int t = 0; t < 2; ++t) {
      int idx = t * 512 + tid;
      int dl = idx >> 3, ch = idx & 7;
      *(us8*)&vtp[(size_t)(dv + dl) * 4096 + m0 + ch * 8] =
          *(const us8*)&Vl[dl * 72 + ch * 8];
    }
  }
#undef PREF_QKV
}

// ---------------- flash (fixed-max, linear, in-block KV-split, w-folded) ----
// grid (64 q-tiles, 8 heads), 512 thr = 8 waves = zg(2) x ih(2) x jq(2).
// Each zg group streams its own KV half (32 steps of 64) into its own K/V
// double buffers; 32 q rows per wave. LDS 73728 B: Q 8K | K 4x8K | V 4x8K
// -> 2 blocks/CU = 16 waves/CU. Epilogue: jq-combine then zg-combine in LDS,
// normalize (O * 1/l), store bf16.

__global__ __launch_bounds__(512, 4) void k_flash(const u16* __restrict__ qk,
                                                  const u16* __restrict__ vt,
                                                  const u16* __restrict__ wpb,
                                                  u16* __restrict__ ao) {
  __shared__ __align__(16) u16 smem[36864];  // 73728 B
  float* bufs = (float*)smem;                // epilogue overlay 4 x 32x65 f32

  const int tid = threadIdx.x;
  const int lane = tid & 63, wave = tid >> 6;
  const int colx = lane & 15, quad = lane >> 4;
  const int zg = wave >> 2;            // kv-half group
  const int ih = (wave >> 1) & 1, jq = wave & 1;
  const int gw = wave & 3;             // wave index within group
  const int q0 = blockIdx.x * 64;
  const int h = blockIdx.y;
  const int kvb = zg * 2048;
  const floatx4 fz = {0.f, 0.f, 0.f, 0.f};

  const int sc = (lane & 7) ^ ((lane >> 3) & 7);
  const int srow = gw * 16 + (lane >> 3);

  // stage Q (swizzled ds_write): 64 rows x 64 cols, one pass of 512 thr
  {
    int row = tid >> 3, ch = tid & 7;
    *(us8*)&smem[row * 64 + (ch ^ (row & 7)) * 8] =
        *(const us8*)&qk[(size_t)(q0 + row) * 1024 + h * 64 + ch * 8];
  }
  // prefetch tile 0 (per group): 4 waves stage 64 K rows + 64 V^T rows
  const u16* qptr = qk + (size_t)(kvb + srow) * 1024 + 512 + h * 64 + sc * 8;
  const u16* vptr = vt + (size_t)(h * 64 + srow) * 4096 + kvb + sc * 8;
  const u16* wptr = wpb + h * 4096 + kvb + jq * 32 + quad * 8;
  gld16(qptr, &smem[4096 + (zg * 2) * 4096 + gw * 1024 + lane * 8]);
  gld16(qptr + 8192, &smem[4096 + (zg * 2) * 4096 + gw * 1024 + 512 + lane * 8]);
  gld16(vptr, &smem[20480 + (zg * 2) * 4096 + gw * 1024 + lane * 8]);
  gld16(vptr + 32768, &smem[20480 + (zg * 2) * 4096 + gw * 1024 + 512 + lane * 8]);
  qptr += 65536;  // 64 kv rows * 1024
  vptr += 64;     // 64 kv cols
  __syncthreads();

  short8 qf[2][2];
#pragma unroll
  for (int iq = 0; iq < 2; ++iq)
#pragma unroll
    for (int kk = 0; kk < 2; ++kk) {
      int row = ih * 32 + iq * 16 + colx;
      qf[iq][kk] = *(const short8*)&smem[row * 64 + (((kk * 4 + quad) ^ (colx & 7))) * 8];
    }

  floatx4 oacc[2][4], lacc[2];
  lacc[0] = fz; lacc[1] = fz;
#pragma unroll
  for (int iq = 0; iq < 2; ++iq)
#pragma unroll
    for (int cb = 0; cb < 4; ++cb) oacc[iq][cb] = fz;

#define FBODY(CUR, PREF)                                                      \
  {                                                                           \
    short8 wf = *(const short8*)wptr;                                         \
    wptr += 64;                                                               \
    if (PREF) {                                                               \
      gld16(qptr, &smem[4096 + (zg * 2 + 1 - (CUR)) * 4096 + gw * 1024 + lane * 8]); \
      gld16(qptr + 8192,                                                      \
            &smem[4096 + (zg * 2 + 1 - (CUR)) * 4096 + gw * 1024 + 512 + lane * 8]); \
      gld16(vptr, &smem[20480 + (zg * 2 + 1 - (CUR)) * 4096 + gw * 1024 + lane * 8]); \
      gld16(vptr + 32768,                                                     \
            &smem[20480 + (zg * 2 + 1 - (CUR)) * 4096 + gw * 1024 + 512 + lane * 8]); \
      qptr += 65536;                                                          \
      vptr += 64;                                                             \
    }                                                                         \
    const u16* Ks = &smem[4096 + (zg * 2 + (CUR)) * 4096];                    \
    const u16* Vts = &smem[20480 + (zg * 2 + (CUR)) * 4096];                  \
    floatx4 sacc[2][2] = {{fz, fz}, {fz, fz}};                                \
    __builtin_amdgcn_s_setprio(1);                                            \
    _Pragma("unroll") for (int j2 = 0; j2 < 2; ++j2) {                        \
      _Pragma("unroll") for (int kk = 0; kk < 2; ++kk) {                      \
        int row = jq * 32 + j2 * 16 + colx;                                   \
        short8 kf = *(const short8*)&Ks[row * 64 +                            \
                                        (((kk * 4 + quad) ^ (colx & 7))) * 8];\
        sacc[0][j2] = __builtin_amdgcn_mfma_f32_16x16x32_bf16(                \
            kf, qf[0][kk], sacc[0][j2], 0, 0, 0);                             \
        sacc[1][j2] = __builtin_amdgcn_mfma_f32_16x16x32_bf16(                \
            kf, qf[1][kk], sacc[1][j2], 0, 0, 0);                             \
      }                                                                       \
    }                                                                         \
    __builtin_amdgcn_s_setprio(0);                                            \
    union { uint32_t w[4]; short8 s; } pk[2];                                 \
    _Pragma("unroll") for (int iq = 0; iq < 2; ++iq) {                        \
      _Pragma("unroll") for (int j2 = 0; j2 < 2; ++j2) {                      \
        float p0 = fexp2(sacc[iq][j2][0]);                                    \
        float p1 = fexp2(sacc[iq][j2][1]);                                    \
        float p2 = fexp2(sacc[iq][j2][2]);                                    \
        float p3 = fexp2(sacc[iq][j2][3]);                                    \
        pk[iq].w[j2 * 2 + 0] = pkbf16(p0, p1);                                \
        pk[iq].w[j2 * 2 + 1] = pkbf16(p2, p3);                                \
      }                                                                       \
    }                                                                         \
    __builtin_amdgcn_s_setprio(1);                                            \
    _Pragma("unroll") for (int cb = 0; cb < 4; ++cb) {                        \
      int row = cb * 16 + colx;                                               \
      short8 vf = *(const short8*)&Vts[row * 64 +                             \
                                       (((jq * 4 + quad) ^ (colx & 7))) * 8]; \
      oacc[0][cb] = __builtin_amdgcn_mfma_f32_16x16x32_bf16(                  \
          pk[0].s, vf, oacc[0][cb], 0, 0, 0);                                 \
      oacc[1][cb] = __builtin_amdgcn_mfma_f32_16x16x32_bf16(                  \
          pk[1].s, vf, oacc[1][cb], 0, 0, 0);                                 \
    }                                                                         \
    lacc[0] = __builtin_amdgcn_mfma_f32_16x16x32_bf16(pk[0].s, wf, lacc[0], 0, 0, 0); \
    lacc[1] = __builtin_amdgcn_mfma_f32_16x16x32_bf16(pk[1].s, wf, lacc[1], 0, 0, 0); \
    __builtin_amdgcn_s_setprio(0);                                            \
    __syncthreads();                                                          \
  }

  for (int t = 0; t < 15; ++t) {
    FBODY(0, 1)
    FBODY(1, 1)
  }
  FBODY(0, 1)
  FBODY(1, 0)
#undef FBODY

  // ---- combine tree ----
  // stage 1 (within zg): jq==1 writes to slot (zg*2+ih); jq==0 adds.
  float* b1 = bufs + (zg * 2 + ih) * 2080;  // 32 rows x 65 f32
  if (jq == 1) {
#pragma unroll
    for (int iq = 0; iq < 2; ++iq)
#pragma unroll
      for (int cb = 0; cb < 4; ++cb)
#pragma unroll
        for (int r = 0; r < 4; ++r)
          b1[(iq * 16 + quad * 4 + r) * 65 + cb * 16 + colx] = oacc[iq][cb][r];
    if (colx == 0)
#pragma unroll
      for (int iq = 0; iq < 2; ++iq)
#pragma unroll
        for (int r = 0; r < 4; ++r) b1[(iq * 16 + quad * 4 + r) * 65 + 64] = lacc[iq][r];
  }
  __syncthreads();
  if (jq == 0) {
#pragma unroll
    for (int iq = 0; iq < 2; ++iq) {
#pragma unroll
      for (int cb = 0; cb < 4; ++cb)
#pragma unroll
        for (int r = 0; r < 4; ++r)
          oacc[iq][cb][r] += b1[(iq * 16 + quad * 4 + r) * 65 + cb * 16 + colx];
#pragma unroll
      for (int r = 0; r < 4; ++r) lacc[iq][r] += b1[(iq * 16 + quad * 4 + r) * 65 + 64];
    }
  }
  __syncthreads();
  // stage 2 (across zg): zg==1,jq==0 writes to slot ih; zg==0,jq==0 combines.
  float* b2 = bufs + ih * 2080;
  if (zg == 1 && jq == 0) {
#pragma unroll
    for (int iq = 0; iq < 2; ++iq)
#pragma unroll
      for (int cb = 0; cb < 4; ++cb)
#pragma unroll
        for (int r = 0; r < 4; ++r)
          b2[(iq * 16 + quad * 4 + r) * 65 + cb * 16 + colx] = oacc[iq][cb][r];
    if (colx == 0)
#pragma unroll
      for (int iq = 0; iq < 2; ++iq)
#pragma unroll
        for (int r = 0; r < 4; ++r) b2[(iq * 16 + quad * 4 + r) * 65 + 64] = lacc[iq][r];
  }
  __syncthreads();
  if (zg == 0 && jq == 0) {
#pragma unroll
    for (int iq = 0; iq < 2; ++iq) {
#pragma unroll
      for (int cb = 0; cb < 4; ++cb)
#pragma unroll
        for (int r = 0; r < 4; ++r)
          oacc[iq][cb][r] += b2[(iq * 16 + quad * 4 + r) * 65 + cb * 16 + colx];
#pragma unroll
      for (int r = 0; r < 4; ++r) lacc[iq][r] += b2[(iq * 16 + quad * 4 + r) * 65 + 64];
    }
#pragma unroll
    for (int iq = 0; iq < 2; ++iq) {
      float inv[4];
#pragma unroll
      for (int r = 0; r < 4; ++r) inv[r] = 1.0f / lacc[iq][r];
#pragma unroll
      for (int cb = 0; cb < 4; ++cb)
#pragma unroll
        for (int r = 0; r < 4; ++r) {
          int row = q0 + ih * 32 + iq * 16 + quad * 4 + r;
          ao[(size_t)row * 512 + h * 64 + cb * 16 + colx] =
              f2b(oacc[iq][cb][r] * inv[r]);
        }
    }
  }
}

// ---------------- out GEMM: 64x64 tile, BK=64, 512 thr, async dbuf ----------

__global__ __launch_bounds__(512, 4) void k_gemm_out(const u16* __restrict__ A,
                                                     const u16* __restrict__ Bt,
                                                     const float* __restrict__ bias,
                                                     float* __restrict__ Cout) {
  __shared__ __align__(16) u16 smem[16384];  // As 2x4096 @0, Bs 2x4096 @8192
  const int tid = threadIdx.x;
  const int lane = tid & 63, wave = tid >> 6;
  const int colx = lane & 15, quad = lane >> 4;
  const int m0 = blockIdx.y * 64, n0 = blockIdx.x * 64;
  const int wm = wave >> 2, wn = wave & 3;
  const int sc = (lane & 7) ^ ((lane >> 3) & 7);
  const floatx4 fz = {0.f, 0.f, 0.f, 0.f};
  floatx4 acc[2];
  acc[0] = fz; acc[1] = fz;

#define PREF_OUT(k0, b)                                                       \
  {                                                                           \
    int rowa = wave * 8 + (lane >> 3);                                        \
    gld16(&A[(size_t)(m0 + rowa) * 512 + (k0) + sc * 8],                      \
          &smem[(b) * 4096 + wave * 512 + lane * 8]);                         \
    gld16(&Bt[(size_t)(n0 + rowa) * 512 + (k0) + sc * 8],                     \
          &smem[8192 + (b) * 4096 + wave * 512 + lane * 8]);                  \
  }

  PREF_OUT(0, 0);
  __syncthreads();
  for (int it = 0; it < 8; ++it) {
    int cur = it & 1;
    if (it < 7) PREF_OUT((it + 1) * 64, cur ^ 1);
    const u16* As = &smem[cur * 4096];
    const u16* Bs = &smem[8192 + cur * 4096];
#pragma unroll
    for (int kk = 0; kk < 2; ++kk) {
      short8 af[2], bf;
#pragma unroll
      for (int i = 0; i < 2; ++i) {
        int row = wm * 32 + i * 16 + colx;
        af[i] = *(const short8*)&As[row * 64 + (((kk * 4 + quad) ^ (colx & 7))) * 8];
      }
      {
        int row = wn * 16 + colx;
        bf = *(const short8*)&Bs[row * 64 + (((kk * 4 + quad) ^ (colx & 7))) * 8];
      }
#pragma unroll
      for (int i = 0; i < 2; ++i)
        acc[i] = __builtin_amdgcn_mfma_f32_16x16x32_bf16(af[i], bf, acc[i], 0, 0, 0);
    }
    __syncthreads();
  }
  int c = n0 + wn * 16 + colx;
  float bq = bias[c];
#pragma unroll
  for (int i = 0; i < 2; ++i)
#pragma unroll
    for (int r = 0; r < 4; ++r) {
      int row = m0 + wm * 32 + i * 16 + quad * 4 + r;
      Cout[(size_t)row * 512 + c] = acc[i][r] + bq;
    }
#undef PREF_OUT
}

// ---------------- launch ----------------

extern "C" void kernel_launch(void* const* d_in, const int* in_sizes, int n_in,
                              void* d_out, int out_size, void* d_ws, size_t ws_size,
                              hipStream_t stream) {
  const float* x     = (const float*)d_in[0];
  const float* pe    = (const float*)d_in[1];
  const float* w_qkv = (const float*)d_in[2];
  const float* b_qkv = (const float*)d_in[3];
  const float* w_pe  = (const float*)d_in[4];
  const float* b_pe  = (const float*)d_in[5];
  const float* w_out = (const float*)d_in[6];
  const float* b_out = (const float*)d_in[7];
  float* out = (float*)d_out;

  // workspace layout
  u16* xb    = (u16*)d_ws;              // 4096*512
  u16* wqkvT = xb    + 2097152;         // 1536*512
  u16* woutT = wqkvT + 786432;          // 512*512
  u16* qk    = woutT + 262144;          // 4096*1024 (Q'|K)
  u16* vt    = qk    + 4194304;         // 512*4096 (pi-permuted w~-folded V'^T)
  u16* wpb   = vt    + 2097152;         // 8*4096 bf16 (pi-permuted w~)
  u16* ao    = wpb   + 32768;           // 4096*512 bf16
  float* wexp  = (float*)(ao + 2097152); // 8*4096 f32 (same w~, expanded)

  k_prep<<<3200, 256, 0, stream>>>(x, xb, w_qkv, wqkvT, w_out, woutT,
                                   pe, w_pe, b_pe, wexp, wpb);
  k_gemm_qkv<<<dim3(12, 64), 512, 0, stream>>>(xb, wqkvT, b_qkv, wexp, qk, vt);
  k_flash<<<dim3(64, 8), 512, 0, stream>>>(qk, vt, wpb, ao);
  k_gemm_out<<<dim3(8, 64), 512, 0, stream>>>(ao, woutT, b_out, out);
}